// Round 2
// baseline (139.280 us; speedup 1.0000x reference)
//
#include <hip/hip_runtime.h>

// Yoshida 4th-order integrator, Gamma(v) = W @ (U v)^2, B=4096, D=1024, R=256.
// R9 = R8 with the VGPR cap actually lifted.
// R8 post-mortem: __launch_bounds__(1024,4) was treated as blocks/CU (clamped
// to 2 -> 8 waves/EU -> 64-VGPR cap); the 64-reg W preload + pipeline buffers
// SPILLED to scratch (WRITE_SIZE 33->75MB, FETCH 52->68MB, dur +6us). A
// 1024-thread block hard-caps at 128 VGPRs (4 waves/EU of a 512-slot file),
// so request minimum occupancy: second arg 1 -> 128-reg cap either way.
// Structure (unchanged from R8):
//  - W slice (16KB/wave) preloaded ONCE into 64 VGPRs: GEMM B has zero global
//    loads; per-step L2 stream halves (512KB -> 256KB per block).
//  - U stream double-buffered in 2-load batches; batch0 issued BEFORE each
//    barrier (loads are step-invariant, no cross-wave dependence).
//  - force -> LDS as f16 (33KB, 2-way banks); xacc -> LDS f32 (lane-private,
//    2-way); x_in load overlaps s==2 GEMM B (off the serial front phase).
//  - last-step vS writeback skipped; final stores fused into s==2 epilogue.
// Kept from R4..R7: fp8 e4m3 MFMA path, 4 packed U/W copies with
// (blockIdx>>3)&3 select, U x8 / W x16 pre-scale, pitches 1040/272.

#define BSZ 4096
#define DD 1024
#define RR 256
#define NCOPY 4
#define COPY_BYTES (512u * 1024u)   // Upk (256KB) + Wpk (256KB) per copy

typedef unsigned char uchar;
typedef long long i64;
typedef __attribute__((ext_vector_type(2))) long i64x2;
typedef __attribute__((ext_vector_type(4))) float f32x4;
typedef __attribute__((ext_vector_type(4))) unsigned int uint4v;
typedef __attribute__((ext_vector_type(4))) _Float16 f16x4;

// pack 4 floats -> 4 fp8 e4m3 bytes (HW cvt, RNE, saturating)
__device__ inline unsigned int f2q4(float a, float b, float c, float d) {
    int lo = __builtin_amdgcn_cvt_pk_fp8_f32(a, b, 0, false);
    int hi = __builtin_amdgcn_cvt_pk_fp8_f32(c, d, lo, true);
    return (unsigned int)hi;
}
__device__ inline uchar f2q1(float x) {
    return (uchar)(__builtin_amdgcn_cvt_pk_fp8_f32(x, x, 0, false) & 0xff);
}

// ---- pack U [R,D] (x8) and W [D,R] (x16) into fragment-major fp8, 4 copies -
// Fragment pair layout: lane l holds 16 bytes = kt=2p (k=kb..kb+7) then
// kt=2p+1 (k=kb+32..kb+39), kb = p*64 + (l>>4)*8; n = tile*16 + (l&15).
__global__ __launch_bounds__(256) void pack_uw_kernel(
    const float* __restrict__ U, const float* __restrict__ W,
    uchar* __restrict__ ws)
{
    const int g = blockIdx.x * 256 + threadIdx.x;
    const float* src;
    size_t off;                         // offset within one copy
    float sc;
    if (g < 16384) {                    // U: 16 nt x 16 p x 64 l
        const int l = g & 63, p = (g >> 6) & 15, nt = g >> 10;
        src = U + (size_t)(nt * 16 + (l & 15)) * DD + p * 64 + (l >> 4) * 8;
        off = ((size_t)nt << 14) + (p << 10) + (l << 4);
        sc = 8.0f;
    } else {                            // W: 64 dtile x 4 p x 64 l
        const int g2 = g - 16384;
        const int l = g2 & 63, p = (g2 >> 6) & 3, dt_ = g2 >> 8;
        src = W + (size_t)(dt_ * 16 + (l & 15)) * RR + p * 64 + (l >> 4) * 8;
        off = (size_t)(256 * 1024) + ((size_t)dt_ << 12) + (p << 10) + (l << 4);
        sc = 16.0f;
    }
    const float4 x0 = *reinterpret_cast<const float4*>(src);
    const float4 x1 = *reinterpret_cast<const float4*>(src + 4);
    const float4 y0 = *reinterpret_cast<const float4*>(src + 32);
    const float4 y1 = *reinterpret_cast<const float4*>(src + 36);
    uint4v o;
    o.x = f2q4(sc * x0.x, sc * x0.y, sc * x0.z, sc * x0.w);
    o.y = f2q4(sc * x1.x, sc * x1.y, sc * x1.z, sc * x1.w);
    o.z = f2q4(sc * y0.x, sc * y0.y, sc * y0.z, sc * y0.w);
    o.w = f2q4(sc * y1.x, sc * y1.y, sc * y1.z, sc * y1.w);
    #pragma unroll
    for (int c = 0; c < NCOPY; ++c)
        *reinterpret_cast<uint4v*>(ws + (size_t)c * COPY_BYTES + off) = o;
}

// ---- fused 3-step integrator ----------------------------------------------
// Second launch-bounds arg = 1: minimum occupancy request -> register
// allocator gets the full 128-VGPR budget this block shape allows.
__global__ __launch_bounds__(1024, 1) void yoshida_fused_kernel(
    const float* __restrict__ x_in,
    const float* __restrict__ v_in,
    const float* __restrict__ force,
    const uchar* __restrict__ ws,
    float* __restrict__ x_out,
    float* __restrict__ v_out)
{
    // byte pitches 1040 / 272 (260 / 68 words, %32==4) -> near-conflict-free
    __shared__ __align__(16) uchar vS[16][1040];
    __shared__ __align__(16) uchar H2S[16][272];
    // force (f16) pitch 1032 halves = 2064B (516 words %32==4) -> 2-way max
    __shared__ __align__(16) _Float16 fS[16][1032];
    // xacc (f32) pitch 1028 words = 4112B (%32==4) -> 2-way max, lane-private
    __shared__ __align__(16) float xaS[16][1028];

    const int tid = threadIdx.x;
    const int w = tid >> 6, l = tid & 63;
    const int m = l & 15, q = l >> 4;
    const int b0 = blockIdx.x * 16;
    const int d0 = w * 64;

    // copy select: varies within an XCD under mod-8 round-robin dispatch
    const uchar* base = ws + (size_t)((blockIdx.x >> 3) & (NCOPY - 1)) * COPY_BYTES;

    constexpr double CBRT2 = 1.2599210498948731647672106072782;
    constexpr double W1c = 1.0 / (2.0 - CBRT2);
    constexpr double W0c = -CBRT2 * W1c;
    constexpr double DTd = 0.01 * 1.0;
    const float dcoef[3] = {(float)(W1c * DTd), (float)(W0c * DTd), (float)(W1c * DTd)};
    const float xcoef[3] = {(float)((W0c + W1c) * 0.5), (float)((W0c + W1c) * 0.5),
                            (float)(W1c * 0.5)};
    const float c1  = (float)(W1c * 0.5);
    const float dtf = (float)DTd;

    const uchar* up = base + ((size_t)w << 14) + (l << 4);          // wave's 16KB U
    const uchar* wp = base + 256 * 1024 + ((size_t)(w * 4) << 12) + (l << 4); // 16KB W

    // --- W preload: 16 x i64x2 = 64 VGPRs, resident for the whole kernel ----
    i64x2 wreg[4][4];
    #pragma unroll
    for (int t = 0; t < 4; ++t)
        #pragma unroll
        for (int p = 0; p < 4; ++p)
            wreg[t][p] = *reinterpret_cast<const i64x2*>(wp + (t << 12) + (p << 10));

    // --- stage v tile into LDS as fp8 (thread = 16 consecutive floats) ------
    {
        const int row = tid >> 6;
        const int col = (tid & 63) * 16;
        const float* sp = v_in + (size_t)(b0 + row) * DD + col;
        const float4 f0 = *reinterpret_cast<const float4*>(sp);
        const float4 f1 = *reinterpret_cast<const float4*>(sp + 4);
        const float4 f2 = *reinterpret_cast<const float4*>(sp + 8);
        const float4 f3 = *reinterpret_cast<const float4*>(sp + 12);
        uint4v pk;
        pk.x = f2q4(f0.x, f0.y, f0.z, f0.w);
        pk.y = f2q4(f1.x, f1.y, f1.z, f1.w);
        pk.z = f2q4(f2.x, f2.y, f2.z, f2.w);
        pk.w = f2q4(f3.x, f3.y, f3.z, f3.w);
        *reinterpret_cast<uint4v*>(&vS[row][col]) = pk;
    }

    // --- stage force tile into LDS as f16 (strided chunks -> 2-4 way banks) -
    {
        const float* sp = force + (size_t)(b0 + w) * DD;
        #pragma unroll
        for (int c = 0; c < 4; ++c) {
            const float4 f = *reinterpret_cast<const float4*>(sp + l * 4 + c * 256);
            f16x4 h;
            h.x = (_Float16)f.x; h.y = (_Float16)f.y;
            h.z = (_Float16)f.z; h.w = (_Float16)f.w;
            *reinterpret_cast<f16x4*>(&fS[w][l * 4 + c * 256]) = h;
        }
    }

    // --- per-lane v state (L2-hot: same lines the staging pass just read) ---
    float vreg[16];
    #pragma unroll
    for (int t = 0; t < 4; ++t)
        #pragma unroll
        for (int i = 0; i < 4; ++i)
            vreg[t * 4 + i] =
                v_in[(size_t)(b0 + q * 4 + i) * DD + d0 + t * 16 + m];

    // --- U batch-0 prefetch (step-invariant addresses, issued pre-barrier) --
    i64x2 ub[2][2];
    ub[0][0] = *reinterpret_cast<const i64x2*>(up);
    ub[0][1] = *reinterpret_cast<const i64x2*>(up + 1024);

    float xreg[16];          // x_in, loaded during s==2 GEMM B only

    #pragma unroll
    for (int s = 0; s < 3; ++s) {
        __syncthreads();   // s==0: vS/fS staged; s>0: epilogue vS writes visible

        // ---- GEMM A: accA = (8U) . v_q, K=1024, U double-buffered 2-wide ----
        f32x4 a0 = {0.f, 0.f, 0.f, 0.f}, a1 = {0.f, 0.f, 0.f, 0.f};
        #pragma unroll
        for (int pb = 0; pb < 8; ++pb) {
            if (pb < 7) {          // prefetch next batch of this step
                ub[(pb + 1) & 1][0] = *reinterpret_cast<const i64x2*>(
                    up + (((pb + 1) * 2 + 0) << 10));
                ub[(pb + 1) & 1][1] = *reinterpret_cast<const i64x2*>(
                    up + (((pb + 1) * 2 + 1) << 10));
            } else if (s < 2) {    // prefetch batch 0 of the NEXT step
                ub[0][0] = *reinterpret_cast<const i64x2*>(up);
                ub[0][1] = *reinterpret_cast<const i64x2*>(up + 1024);
            }
            #pragma unroll
            for (int j = 0; j < 2; ++j) {
                const int p = pb * 2 + j;
                const i64 af0 = *reinterpret_cast<const i64*>(&vS[m][p * 64 + q * 8]);
                const i64 af1 = *reinterpret_cast<const i64*>(&vS[m][p * 64 + 32 + q * 8]);
                a0 = __builtin_amdgcn_mfma_f32_16x16x32_fp8_fp8(
                         af0, ub[pb & 1][j].x, a0, 0, 0, 0);
                a1 = __builtin_amdgcn_mfma_f32_16x16x32_fp8_fp8(
                         af1, ub[pb & 1][j].y, a1, 0, 0, 0);
            }
        }
        #pragma unroll
        for (int i = 0; i < 4; ++i) {
            const float h8 = a0[i] + a1[i];                    // = 8*h
            H2S[q * 4 + i][w * 16 + m] = f2q1(h8 * h8 * 0.015625f);  // h^2
        }
        __syncthreads();   // H2S published

        // x_in loads overlap s==2 GEMM B + epilogue (U-stream regs are idle)
        if (s == 2) {
            #pragma unroll
            for (int t = 0; t < 4; ++t)
                #pragma unroll
                for (int i = 0; i < 4; ++i)
                    xreg[t * 4 + i] =
                        x_in[(size_t)(b0 + q * 4 + i) * DD + d0 + t * 16 + m];
        }

        // ---- GEMM B: accB = (16W) . h2_q, K=256 — W in registers, no loads -
        f32x4 accB[4];
        #pragma unroll
        for (int t = 0; t < 4; ++t) accB[t] = (f32x4){0.f, 0.f, 0.f, 0.f};
        #pragma unroll
        for (int p = 0; p < 4; ++p) {
            const i64 ha0 = *reinterpret_cast<const i64*>(&H2S[m][p * 64 + q * 8]);
            const i64 ha1 = *reinterpret_cast<const i64*>(&H2S[m][p * 64 + 32 + q * 8]);
            #pragma unroll
            for (int t = 0; t < 4; ++t) {
                accB[t] = __builtin_amdgcn_mfma_f32_16x16x32_fp8_fp8(
                              ha0, wreg[t][p].x, accB[t], 0, 0, 0);
                accB[t] = __builtin_amdgcn_mfma_f32_16x16x32_fp8_fp8(
                              ha1, wreg[t][p].y, accB[t], 0, 0, 0);
            }
        }

        // ---- epilogue: v += ddt*f - (ddt/16)*accB; xacc in LDS; vS <- fp8(v)
        const float ddt = dcoef[s], cx = xcoef[s], gsc = dcoef[s] * 0.0625f;
        #pragma unroll
        for (int t = 0; t < 4; ++t)
            #pragma unroll
            for (int i = 0; i < 4; ++i) {
                const int r = q * 4 + i, c = d0 + t * 16 + m;
                const float ff = (float)fS[r][c];
                const float vold = vreg[t * 4 + i];
                const float vn = vold + ddt * ff - gsc * accB[t][i];
                vreg[t * 4 + i] = vn;
                if (s == 0) {
                    xaS[r][c] = c1 * vold + cx * vn;
                    vS[r][c] = f2q1(vn);
                } else if (s == 1) {
                    xaS[r][c] += cx * vn;
                    vS[r][c] = f2q1(vn);
                } else {
                    const float xa = xaS[r][c] + cx * vn;
                    const size_t g = (size_t)(b0 + r) * DD + c;
                    x_out[g] = xreg[t * 4 + i] + dtf * xa;
                    v_out[g] = vn;
                }
            }
    }
}

extern "C" void kernel_launch(void* const* d_in, const int* in_sizes, int n_in,
                              void* d_out, int out_size, void* d_ws, size_t ws_size,
                              hipStream_t stream) {
    const float* x     = (const float*)d_in[0];
    const float* v     = (const float*)d_in[1];
    const float* force = (const float*)d_in[2];
    const float* U     = (const float*)d_in[3];
    const float* W     = (const float*)d_in[4];

    float* x_out = (float*)d_out;
    float* v_out = x_out + (size_t)BSZ * DD;

    uchar* ws = (uchar*)d_ws;   // NCOPY x 512KB packed copies (2 MB)

    pack_uw_kernel<<<dim3(128), dim3(256), 0, stream>>>(U, W, ws);
    yoshida_fused_kernel<<<dim3(BSZ / 16), dim3(1024), 0, stream>>>(
        x, v, force, ws, x_out, v_out);
}

// Round 3
// 126.202 us; speedup vs baseline: 1.1036x; 1.1036x over previous
//
#include <hip/hip_runtime.h>

// Yoshida 4th-order integrator, Gamma(v) = W @ (U v)^2, B=4096, D=1024, R=256.
// R10: back inside the proven 64-arch-VGPR envelope (R8/R9 post-mortem: 1024-
// thread MFMA kernels get a hard 64/64 VGPR/AGPR split on this toolchain; the
// 64-reg W preload spilled ~67MB to scratch both times). Keep R8's register-
// FREEING ideas, drop the register-HUNGRY one, spend the headroom on in-flight
// load depth:
//  - force -> LDS f16 (33KB), xacc -> LDS f32 (66KB): frees 32 regs of state.
//  - U stream 4-deep double-buffer (16 regs): load p+4 during MFMA p; next
//    step's first 4 U loads issued at the END of the prior epilogue so they
//    are in flight across the barrier.
//  - W stream 2-deep 4-load chunks (32 regs, live only in GEMM B); chunk 0
//    issued before the H2S barrier (U buffer dead there).
//  - x_in read moved to after GEMM B of s==2 (off the serial front phase);
//    last-step vS writeback skipped; stores fused into s==2 epilogue.
// Front phase shrinks 52 -> ~24 load instrs/thread.
// Kept from R4..R7: fp8 e4m3 MFMA path, 4 packed U/W copies with
// (blockIdx>>3)&3 select, U x8 / W x16 pre-scale, pitches 1040/272.

#define BSZ 4096
#define DD 1024
#define RR 256
#define NCOPY 4
#define COPY_BYTES (512u * 1024u)   // Upk (256KB) + Wpk (256KB) per copy

typedef unsigned char uchar;
typedef long long i64;
typedef __attribute__((ext_vector_type(2))) long i64x2;
typedef __attribute__((ext_vector_type(4))) float f32x4;
typedef __attribute__((ext_vector_type(4))) unsigned int uint4v;
typedef __attribute__((ext_vector_type(4))) _Float16 f16x4;

// pack 4 floats -> 4 fp8 e4m3 bytes (HW cvt, RNE, saturating)
__device__ inline unsigned int f2q4(float a, float b, float c, float d) {
    int lo = __builtin_amdgcn_cvt_pk_fp8_f32(a, b, 0, false);
    int hi = __builtin_amdgcn_cvt_pk_fp8_f32(c, d, lo, true);
    return (unsigned int)hi;
}
__device__ inline uchar f2q1(float x) {
    return (uchar)(__builtin_amdgcn_cvt_pk_fp8_f32(x, x, 0, false) & 0xff);
}

// ---- pack U [R,D] (x8) and W [D,R] (x16) into fragment-major fp8, 4 copies -
// Fragment pair layout: lane l holds 16 bytes = kt=2p (k=kb..kb+7) then
// kt=2p+1 (k=kb+32..kb+39), kb = p*64 + (l>>4)*8; n = tile*16 + (l&15).
__global__ __launch_bounds__(256) void pack_uw_kernel(
    const float* __restrict__ U, const float* __restrict__ W,
    uchar* __restrict__ ws)
{
    const int g = blockIdx.x * 256 + threadIdx.x;
    const float* src;
    size_t off;                         // offset within one copy
    float sc;
    if (g < 16384) {                    // U: 16 nt x 16 p x 64 l
        const int l = g & 63, p = (g >> 6) & 15, nt = g >> 10;
        src = U + (size_t)(nt * 16 + (l & 15)) * DD + p * 64 + (l >> 4) * 8;
        off = ((size_t)nt << 14) + (p << 10) + (l << 4);
        sc = 8.0f;
    } else {                            // W: 64 dtile x 4 p x 64 l
        const int g2 = g - 16384;
        const int l = g2 & 63, p = (g2 >> 6) & 3, dt_ = g2 >> 8;
        src = W + (size_t)(dt_ * 16 + (l & 15)) * RR + p * 64 + (l >> 4) * 8;
        off = (size_t)(256 * 1024) + ((size_t)dt_ << 12) + (p << 10) + (l << 4);
        sc = 16.0f;
    }
    const float4 x0 = *reinterpret_cast<const float4*>(src);
    const float4 x1 = *reinterpret_cast<const float4*>(src + 4);
    const float4 y0 = *reinterpret_cast<const float4*>(src + 32);
    const float4 y1 = *reinterpret_cast<const float4*>(src + 36);
    uint4v o;
    o.x = f2q4(sc * x0.x, sc * x0.y, sc * x0.z, sc * x0.w);
    o.y = f2q4(sc * x1.x, sc * x1.y, sc * x1.z, sc * x1.w);
    o.z = f2q4(sc * y0.x, sc * y0.y, sc * y0.z, sc * y0.w);
    o.w = f2q4(sc * y1.x, sc * y1.y, sc * y1.z, sc * y1.w);
    #pragma unroll
    for (int c = 0; c < NCOPY; ++c)
        *reinterpret_cast<uint4v*>(ws + (size_t)c * COPY_BYTES + off) = o;
}

// ---- fused 3-step integrator ----------------------------------------------
__global__ __launch_bounds__(1024) void yoshida_fused_kernel(
    const float* __restrict__ x_in,
    const float* __restrict__ v_in,
    const float* __restrict__ force,
    const uchar* __restrict__ ws,
    float* __restrict__ x_out,
    float* __restrict__ v_out)
{
    // byte pitches 1040 / 272 (260 / 68 words, %32==4) -> near-conflict-free
    __shared__ __align__(16) uchar vS[16][1040];
    __shared__ __align__(16) uchar H2S[16][272];
    // force (f16) pitch 1032 halves = 2064B (516 words %32==4) -> 2-way max
    __shared__ __align__(16) _Float16 fS[16][1032];
    // xacc (f32) pitch 1028 words = 4112B (%32==4) -> 2-way max, lane-private
    __shared__ __align__(16) float xaS[16][1028];

    const int tid = threadIdx.x;
    const int w = tid >> 6, l = tid & 63;
    const int m = l & 15, q = l >> 4;
    const int b0 = blockIdx.x * 16;
    const int d0 = w * 64;

    // copy select: varies within an XCD under mod-8 round-robin dispatch
    const uchar* base = ws + (size_t)((blockIdx.x >> 3) & (NCOPY - 1)) * COPY_BYTES;

    constexpr double CBRT2 = 1.2599210498948731647672106072782;
    constexpr double W1c = 1.0 / (2.0 - CBRT2);
    constexpr double W0c = -CBRT2 * W1c;
    constexpr double DTd = 0.01 * 1.0;
    const float dcoef[3] = {(float)(W1c * DTd), (float)(W0c * DTd), (float)(W1c * DTd)};
    const float xcoef[3] = {(float)((W0c + W1c) * 0.5), (float)((W0c + W1c) * 0.5),
                            (float)(W1c * 0.5)};
    const float c1  = (float)(W1c * 0.5);
    const float dtf = (float)DTd;

    const uchar* up = base + ((size_t)w << 14) + (l << 4);          // wave's 16KB U
    const uchar* wp = base + 256 * 1024 + ((size_t)(w * 4) << 12) + (l << 4); // 16KB W

    // --- stage v tile into LDS as fp8 (thread = 16 consecutive floats) ------
    {
        const int row = tid >> 6;
        const int col = (tid & 63) * 16;
        const float* sp = v_in + (size_t)(b0 + row) * DD + col;
        const float4 f0 = *reinterpret_cast<const float4*>(sp);
        const float4 f1 = *reinterpret_cast<const float4*>(sp + 4);
        const float4 f2 = *reinterpret_cast<const float4*>(sp + 8);
        const float4 f3 = *reinterpret_cast<const float4*>(sp + 12);
        uint4v pk;
        pk.x = f2q4(f0.x, f0.y, f0.z, f0.w);
        pk.y = f2q4(f1.x, f1.y, f1.z, f1.w);
        pk.z = f2q4(f2.x, f2.y, f2.z, f2.w);
        pk.w = f2q4(f3.x, f3.y, f3.z, f3.w);
        *reinterpret_cast<uint4v*>(&vS[row][col]) = pk;
    }

    // --- stage force tile into LDS as f16 (strided chunks -> 2-way banks) ---
    {
        const float* sp = force + (size_t)(b0 + w) * DD;
        #pragma unroll
        for (int c = 0; c < 4; ++c) {
            const float4 f = *reinterpret_cast<const float4*>(sp + l * 4 + c * 256);
            f16x4 h;
            h.x = (_Float16)f.x; h.y = (_Float16)f.y;
            h.z = (_Float16)f.z; h.w = (_Float16)f.w;
            *reinterpret_cast<f16x4*>(&fS[w][l * 4 + c * 256]) = h;
        }
    }

    // --- per-lane v state (L2-hot: same lines the staging pass just read) ---
    float vreg[16];
    #pragma unroll
    for (int t = 0; t < 4; ++t)
        #pragma unroll
        for (int i = 0; i < 4; ++i)
            vreg[t * 4 + i] =
                v_in[(size_t)(b0 + q * 4 + i) * DD + d0 + t * 16 + m];

    // --- U pipeline: 4-deep rotation; slots 0..3 issued pre-barrier ---------
    i64x2 ub[4];
    #pragma unroll
    for (int p = 0; p < 4; ++p)
        ub[p] = *reinterpret_cast<const i64x2*>(up + (p << 10));

    #pragma unroll
    for (int s = 0; s < 3; ++s) {
        __syncthreads();   // s==0: vS/fS staged; s>0: epilogue vS writes visible

        // ---- GEMM A: accA = (8U) . v_q, K=1024, U 4-deep pipelined ----------
        f32x4 a0 = {0.f, 0.f, 0.f, 0.f}, a1 = {0.f, 0.f, 0.f, 0.f};
        #pragma unroll
        for (int p = 0; p < 16; ++p) {
            i64x2 nxt;
            if (p < 12)
                nxt = *reinterpret_cast<const i64x2*>(up + ((p + 4) << 10));
            const i64 af0 = *reinterpret_cast<const i64*>(&vS[m][p * 64 + q * 8]);
            const i64 af1 = *reinterpret_cast<const i64*>(&vS[m][p * 64 + 32 + q * 8]);
            a0 = __builtin_amdgcn_mfma_f32_16x16x32_fp8_fp8(af0, ub[p & 3].x, a0, 0, 0, 0);
            a1 = __builtin_amdgcn_mfma_f32_16x16x32_fp8_fp8(af1, ub[p & 3].y, a1, 0, 0, 0);
            if (p < 12)
                ub[p & 3] = nxt;
        }
        #pragma unroll
        for (int i = 0; i < 4; ++i) {
            const float h8 = a0[i] + a1[i];                    // = 8*h
            H2S[q * 4 + i][w * 16 + m] = f2q1(h8 * h8 * 0.015625f);  // h^2
        }

        // W chunk 0 issued before the barrier (U regs dead, hides L2 latency)
        i64x2 wb[2][4];
        #pragma unroll
        for (int t = 0; t < 4; ++t)
            wb[0][t] = *reinterpret_cast<const i64x2*>(wp + (t << 12));

        __syncthreads();   // H2S published

        // ---- GEMM B: accB = (16W) . h2_q, K=256, W 2-deep chunked ----------
        f32x4 accB[4];
        #pragma unroll
        for (int t = 0; t < 4; ++t) accB[t] = (f32x4){0.f, 0.f, 0.f, 0.f};
        #pragma unroll
        for (int p = 0; p < 4; ++p) {
            if (p < 3) {
                #pragma unroll
                for (int t = 0; t < 4; ++t)
                    wb[(p + 1) & 1][t] = *reinterpret_cast<const i64x2*>(
                        wp + (t << 12) + ((p + 1) << 10));
            }
            const i64 ha0 = *reinterpret_cast<const i64*>(&H2S[m][p * 64 + q * 8]);
            const i64 ha1 = *reinterpret_cast<const i64*>(&H2S[m][p * 64 + 32 + q * 8]);
            #pragma unroll
            for (int t = 0; t < 4; ++t) {
                accB[t] = __builtin_amdgcn_mfma_f32_16x16x32_fp8_fp8(
                              ha0, wb[p & 1][t].x, accB[t], 0, 0, 0);
                accB[t] = __builtin_amdgcn_mfma_f32_16x16x32_fp8_fp8(
                              ha1, wb[p & 1][t].y, accB[t], 0, 0, 0);
            }
        }

        // x_in loads only now (s==2): off the front phase, overlap epilogue
        float xreg[16];
        if (s == 2) {
            #pragma unroll
            for (int t = 0; t < 4; ++t)
                #pragma unroll
                for (int i = 0; i < 4; ++i)
                    xreg[t * 4 + i] =
                        x_in[(size_t)(b0 + q * 4 + i) * DD + d0 + t * 16 + m];
        }

        // ---- epilogue: v += ddt*f - (ddt/16)*accB; xacc in LDS; vS <- fp8(v)
        const float ddt = dcoef[s], cx = xcoef[s], gsc = dcoef[s] * 0.0625f;
        #pragma unroll
        for (int t = 0; t < 4; ++t)
            #pragma unroll
            for (int i = 0; i < 4; ++i) {
                const int r = q * 4 + i, c = d0 + t * 16 + m;
                const float ff = (float)fS[r][c];
                const float vold = vreg[t * 4 + i];
                const float vn = vold + ddt * ff - gsc * accB[t][i];
                vreg[t * 4 + i] = vn;
                if (s == 0) {
                    xaS[r][c] = c1 * vold + cx * vn;
                    vS[r][c] = f2q1(vn);
                } else if (s == 1) {
                    xaS[r][c] += cx * vn;
                    vS[r][c] = f2q1(vn);
                } else {
                    const float xa = xaS[r][c] + cx * vn;
                    const size_t g = (size_t)(b0 + r) * DD + c;
                    x_out[g] = xreg[t * 4 + i] + dtf * xa;
                    v_out[g] = vn;
                }
            }

        // next step's first U chunk: in flight across the coming barrier
        if (s < 2) {
            #pragma unroll
            for (int p = 0; p < 4; ++p)
                ub[p] = *reinterpret_cast<const i64x2*>(up + (p << 10));
        }
    }
}

extern "C" void kernel_launch(void* const* d_in, const int* in_sizes, int n_in,
                              void* d_out, int out_size, void* d_ws, size_t ws_size,
                              hipStream_t stream) {
    const float* x     = (const float*)d_in[0];
    const float* v     = (const float*)d_in[1];
    const float* force = (const float*)d_in[2];
    const float* U     = (const float*)d_in[3];
    const float* W     = (const float*)d_in[4];

    float* x_out = (float*)d_out;
    float* v_out = x_out + (size_t)BSZ * DD;

    uchar* ws = (uchar*)d_ws;   // NCOPY x 512KB packed copies (2 MB)

    pack_uw_kernel<<<dim3(128), dim3(256), 0, stream>>>(U, W, ws);
    yoshida_fused_kernel<<<dim3(BSZ / 16), dim3(1024), 0, stream>>>(
        x, v, force, ws, x_out, v_out);
}